// Round 1
// 24996.170 us; speedup vs baseline: 2.0073x; 2.0073x over previous
//
#include <hip/hip_runtime.h>
#include <hip/hip_bf16.h>
#include <math.h>

typedef __hip_bfloat16 bf16;     // legacy kernels (attn)
typedef __bf16 bf16t;            // native bf16 for MFMA path (same bits)
typedef __attribute__((ext_vector_type(8))) __bf16 bf16x8;
typedef __attribute__((ext_vector_type(16))) float f32x16;

#define E_DIM 768
#define HEADS 12
#define DHEAD 64
#define LAYERS 12
#define NTOK 197
#define BATCH 64
#define EPSV 1e-5f

__device__ __forceinline__ float b2f(bf16 v) { return __bfloat162float(v); }

// ---------------- im2col for patch embedding ----------------
// P[m][k], m = bl*196 + pidx, k = c*256 + py*16 + px. Each thread copies 8 floats.
__global__ __launch_bounds__(256) void im2col_k(const float* __restrict__ x,
                                                float* __restrict__ P,
                                                int b0, int M) {
    int task = blockIdx.x * 256 + threadIdx.x;
    if (task >= M * 96) return;
    int m = task / 96;
    int kg = task - m * 96;
    int k0 = kg * 8;
    int c = k0 >> 8, py = (k0 >> 4) & 15, px = k0 & 15;
    int bl = m / 196, pidx = m - bl * 196;
    int ph = pidx / 14, pw = pidx - ph * 14;
    const float* src = x + ((size_t)((b0 + bl) * 3 + c) * 224 + (ph * 16 + py)) * 224
                         + pw * 16 + px;
    const float4* s4 = reinterpret_cast<const float4*>(src);
    float4* d4 = reinterpret_cast<float4*>(P + (size_t)m * 768 + k0);
    d4[0] = s4[0];
    d4[1] = s4[1];
}

// cls token: h[b][0][e] = cls[e] + pos[0][e].
__global__ void embed_cls(const float* __restrict__ cls, const float* __restrict__ pos,
                          float* __restrict__ h) {
    int b = blockIdx.x, e = threadIdx.x;
    h[(size_t)b * NTOK * 768 + e] = cls[e] + pos[e];
}

// ---------------- layernorm over E=768 ----------------
__global__ __launch_bounds__(256) void layernorm_k(
    const float* __restrict__ h, float* __restrict__ y,
    const float* __restrict__ s, const float* __restrict__ bsh) {
    int tok = blockIdx.x, t = threadIdx.x;
    const float* row = h + (size_t)tok * 768;
    float v0 = row[t], v1 = row[t + 256], v2 = row[t + 512];
    __shared__ float red[256];
    red[t] = v0 + v1 + v2;
    __syncthreads();
    for (int o = 128; o > 0; o >>= 1) { if (t < o) red[t] += red[t + o]; __syncthreads(); }
    float mean = red[0] * (1.f / 768.f);
    __syncthreads();
    red[t] = v0 * v0 + v1 * v1 + v2 * v2;
    __syncthreads();
    for (int o = 128; o > 0; o >>= 1) { if (t < o) red[t] += red[t + o]; __syncthreads(); }
    float var = red[0] * (1.f / 768.f) - mean * mean;
    float rs = rsqrtf(var + EPSV);
    float* yr = y + (size_t)tok * 768;
    yr[t]       = (v0 - mean) * rs * s[t]       + bsh[t];
    yr[t + 256] = (v1 - mean) * rs * s[t + 256] + bsh[t + 256];
    yr[t + 512] = (v2 - mean) * rs * s[t + 512] + bsh[t + 512];
}

// ---------------- MFMA GEMM, split-bf16 accumulation ----------------
// C[m,n] = sum_k A[m,k] * W[k,n] (+bias)(+gelu)(+resid)
// 128x128 tile, BK=32, 4 waves of 64x64, v_mfma_f32_32x32x16_bf16.
// TERMS=3: AhiWhi + AhiWlo + AloWhi (fp32-level accuracy, fp32 A)
// TERMS=2: AhiWhi + AhiWlo          (A already bf16)
// flags: 1=gelu, 2=perHead(qkv W layout [H][K][192], N flattened 2304),
//        4=wTrans (W stored [N][K], e.g. conv_w), 8=embedOut (row remap + pos via resid)
#define PLANE 2064   // bytes per k-group plane: 128 rows * 16B + 16B pad

__device__ __forceinline__ f32x16 mfma_bf16(bf16x8 a, bf16x8 b, f32x16 c) {
    return __builtin_amdgcn_mfma_f32_32x32x16_bf16(a, b, c, 0, 0, 0);
}

__device__ __forceinline__ f32x16 zero16() {
    f32x16 z;
#pragma unroll
    for (int i = 0; i < 16; ++i) z[i] = 0.f;
    return z;
}

__device__ __forceinline__ void split8(float4 u0, float4 u1, bf16x8& hi, bf16x8& lo) {
    float f[8] = {u0.x, u0.y, u0.z, u0.w, u1.x, u1.y, u1.z, u1.w};
#pragma unroll
    for (int j = 0; j < 8; ++j) {
        __bf16 h = (__bf16)f[j];
        hi[j] = h;
        lo[j] = (__bf16)(f[j] - (float)h);
    }
}

template <typename AT, typename CT, int TERMS>
__global__ __launch_bounds__(256, 2) void gemm_mfma(
    const AT* __restrict__ A, int lda,
    const float* __restrict__ W, int ldw,
    const float* __restrict__ bias,
    const float* __restrict__ resid,
    CT* __restrict__ C, int ldc,
    int M, int K, int flags) {
    constexpr bool SPLIT_A = (TERMS >= 3);
    const int gelu = flags & 1, perHead = flags & 2, wTrans = flags & 4, embedOut = flags & 8;
    const int n0 = blockIdx.x * 128, m0 = blockIdx.y * 128;
    const int t = threadIdx.x;

    __shared__ __align__(16) char smem[SPLIT_A ? 4 * 8256 : 3 * 8256];
    char* sAh = smem;
    char* sWh = smem + 8256;
    char* sWl = smem + 16512;
    char* sAl = SPLIT_A ? smem + 24768 : smem;

    // ---- staging task descriptors: 2 tasks/thread, task q: row=q&127, kg=q>>7 ----
    const AT* aptr[2]; int aoff[2]; bool aok[2];
    const float* wptr[2]; int woff[2];
    const size_t wstep = perHead ? 192 : (size_t)ldw;
#pragma unroll
    for (int p = 0; p < 2; ++p) {
        int q = t + p * 256;
        int rn = q & 127, kg = q >> 7;
        int gm = m0 + rn;
        aok[p] = gm < M;
        aptr[p] = A + (size_t)(aok[p] ? gm : 0) * lda + kg * 8;
        aoff[p] = kg * PLANE + rn * 16;
        woff[p] = kg * PLANE + rn * 16;
        if (wTrans) {
            wptr[p] = W + (size_t)(n0 + rn) * ldw + kg * 8;
        } else if (perHead) {
            int gn = n0 + rn;
            int hh = gn / 192;
            wptr[p] = W + (size_t)hh * K * 192 + (gn - hh * 192) + (size_t)(kg * 8) * 192;
        } else {
            wptr[p] = W + (n0 + rn) + (size_t)(kg * 8) * ldw;
        }
    }

    // ---- compute-lane constants ----
    const int lane = t & 63, wv = t >> 6;
    const int wm = wv >> 1, wn = wv & 1;
    const int lr = lane & 31, lk = lane >> 5;
    const int arow0 = (wm * 64 + lr) * 16;   // byte offset in plane, mf=0 (mf=1: +512)
    const int brow0 = (wn * 64 + lr) * 16;
    f32x16 acc00 = zero16(), acc01 = zero16(), acc10 = zero16(), acc11 = zero16();

    const int nIt = K >> 5;
    for (int it = 0; it < nIt; ++it) {
        const int k0 = it << 5;
        __syncthreads();
        // ---- stage A ----
#pragma unroll
        for (int p = 0; p < 2; ++p) {
            if constexpr (sizeof(AT) == 4) {
                float4 u0 = make_float4(0.f, 0.f, 0.f, 0.f), u1 = u0;
                if (aok[p]) {
                    const float4* s4 = reinterpret_cast<const float4*>(aptr[p] + k0);
                    u0 = s4[0]; u1 = s4[1];
                }
                bf16x8 hi, lo;
                split8(u0, u1, hi, lo);
                *reinterpret_cast<bf16x8*>(sAh + aoff[p]) = hi;
                if constexpr (SPLIT_A) *reinterpret_cast<bf16x8*>(sAl + aoff[p]) = lo;
            } else {
                bf16x8 hi;
                if (aok[p]) hi = *reinterpret_cast<const bf16x8*>(aptr[p] + k0);
                else {
#pragma unroll
                    for (int j = 0; j < 8; ++j) hi[j] = (__bf16)0.f;
                }
                *reinterpret_cast<bf16x8*>(sAh + aoff[p]) = hi;
            }
        }
        // ---- stage W (always split) ----
#pragma unroll
        for (int p = 0; p < 2; ++p) {
            bf16x8 hi, lo;
            if (wTrans) {
                const float4* s4 = reinterpret_cast<const float4*>(wptr[p] + k0);
                split8(s4[0], s4[1], hi, lo);
            } else {
                const float* s = wptr[p] + (size_t)k0 * wstep;
                float4 u0, u1;
                u0.x = s[0];         u0.y = s[wstep];     u0.z = s[2 * wstep]; u0.w = s[3 * wstep];
                u1.x = s[4 * wstep]; u1.y = s[5 * wstep]; u1.z = s[6 * wstep]; u1.w = s[7 * wstep];
                split8(u0, u1, hi, lo);
            }
            *reinterpret_cast<bf16x8*>(sWh + woff[p]) = hi;
            *reinterpret_cast<bf16x8*>(sWl + woff[p]) = lo;
        }
        __syncthreads();
        // ---- compute ----
#pragma unroll
        for (int ks = 0; ks < 2; ++ks) {
            const int kg = ks * 2 + lk;
            const char* pa  = sAh + kg * PLANE;
            const char* pb  = sWh + kg * PLANE;
            const char* pbl = sWl + kg * PLANE;
            bf16x8 ah0 = *reinterpret_cast<const bf16x8*>(pa + arow0);
            bf16x8 ah1 = *reinterpret_cast<const bf16x8*>(pa + arow0 + 512);
            bf16x8 bh0 = *reinterpret_cast<const bf16x8*>(pb + brow0);
            bf16x8 bh1 = *reinterpret_cast<const bf16x8*>(pb + brow0 + 512);
            bf16x8 bl0 = *reinterpret_cast<const bf16x8*>(pbl + brow0);
            bf16x8 bl1 = *reinterpret_cast<const bf16x8*>(pbl + brow0 + 512);
            acc00 = mfma_bf16(ah0, bh0, acc00);
            acc01 = mfma_bf16(ah0, bh1, acc01);
            acc10 = mfma_bf16(ah1, bh0, acc10);
            acc11 = mfma_bf16(ah1, bh1, acc11);
            acc00 = mfma_bf16(ah0, bl0, acc00);
            acc01 = mfma_bf16(ah0, bl1, acc01);
            acc10 = mfma_bf16(ah1, bl0, acc10);
            acc11 = mfma_bf16(ah1, bl1, acc11);
            if constexpr (SPLIT_A) {
                const char* pal = sAl + kg * PLANE;
                bf16x8 al0 = *reinterpret_cast<const bf16x8*>(pal + arow0);
                bf16x8 al1 = *reinterpret_cast<const bf16x8*>(pal + arow0 + 512);
                acc00 = mfma_bf16(al0, bh0, acc00);
                acc01 = mfma_bf16(al0, bh1, acc01);
                acc10 = mfma_bf16(al1, bh0, acc10);
                acc11 = mfma_bf16(al1, bh1, acc11);
            }
        }
    }

    // ---- epilogue ----
    // C/D layout (m74/m101): col = lane&31, row = (r&3) + 8*(r>>2) + 4*(lane>>5)
    const int gcol0 = n0 + wn * 64 + lr;
#define EPILOG(ACC, MF, NF)                                                         \
    {                                                                               \
        int gcol = gcol0 + (NF) * 32;                                               \
        float bv = bias[gcol];                                                      \
        _Pragma("unroll")                                                           \
        for (int r = 0; r < 16; ++r) {                                              \
            int grow = m0 + wm * 64 + (MF) * 32 + (r & 3) + 8 * (r >> 2) + 4 * lk;  \
            if (grow < M) {                                                         \
                float val = ACC[r] + bv;                                            \
                if (gelu) val = 0.5f * val * (1.f + erff(val * 0.70710678f));       \
                if (embedOut) {                                                     \
                    int bl2 = grow / 196;                                           \
                    int pidx = grow - bl2 * 196;                                    \
                    val += resid[(size_t)(pidx + 1) * 768 + gcol];                  \
                    C[((size_t)bl2 * 197 + pidx + 1) * ldc + gcol] = (CT)val;       \
                } else {                                                            \
                    if (resid) val += resid[(size_t)grow * ldc + gcol];             \
                    C[(size_t)grow * ldc + gcol] = (CT)val;                         \
                }                                                                   \
            }                                                                       \
        }                                                                           \
    }
    EPILOG(acc00, 0, 0)
    EPILOG(acc01, 0, 1)
    EPILOG(acc10, 1, 0)
    EPILOG(acc11, 1, 1)
#undef EPILOG
}

// ---------------- fused attention: scores -> softmax -> PV ----------------
// qkv layout (bf16): [Mr, H*192], element (h, 3d+{0,1,2}) = q/k/v
#define ITILE 8
__global__ __launch_bounds__(256) void attn_k(const bf16* __restrict__ qkv,
                                              bf16* __restrict__ att) {
    int it = blockIdx.x, hh = blockIdx.y, b = blockIdx.z;
    int i0 = it * ITILE;
    int nrow = NTOK - i0; if (nrow > ITILE) nrow = ITILE;
    int t = threadIdx.x;
    const bf16* base = qkv + (size_t)b * NTOK * 2304 + hh * 192;

    __shared__ float q[ITILE][DHEAD];
    __shared__ float p[ITILE][NTOK];

    for (int idx = t; idx < ITILE * DHEAD; idx += 256) {
        int i = idx >> 6, d = idx & 63;
        q[i][d] = (i < nrow) ? b2f(base[(long)(i0 + i) * 2304 + 3 * d]) : 0.f;
    }
    __syncthreads();

    if (t < NTOK) {
        const bf16* krow = base + (long)t * 2304 + 1;
        float acc[ITILE] = {};
        for (int d = 0; d < DHEAD; ++d) {
            float kv = b2f(krow[3 * d]);
#pragma unroll
            for (int i = 0; i < ITILE; ++i) acc[i] += q[i][d] * kv;
        }
#pragma unroll
        for (int i = 0; i < ITILE; ++i) p[i][t] = acc[i] * 0.125f;
    }
    __syncthreads();

    int w = t >> 6, lane = t & 63;
    for (int i = w; i < nrow; i += 4) {
        float m = -1e30f;
        for (int j = lane; j < NTOK; j += 64) m = fmaxf(m, p[i][j]);
        for (int off = 32; off; off >>= 1) m = fmaxf(m, __shfl_xor(m, off));
        float ssum = 0.f;
        for (int j = lane; j < NTOK; j += 64) { float e = __expf(p[i][j] - m); p[i][j] = e; ssum += e; }
        for (int off = 32; off; off >>= 1) ssum += __shfl_xor(ssum, off);
        float inv = 1.f / ssum;
        for (int j = lane; j < NTOK; j += 64) p[i][j] *= inv;
    }
    __syncthreads();

    const bf16* vcol = base + 3 * lane + 2;
    for (int i = w; i < nrow; i += 4) {
        float o = 0.f;
        for (int j = 0; j < NTOK; ++j) o += p[i][j] * b2f(vcol[(long)j * 2304]);
        att[((size_t)b * NTOK + i0 + i) * 768 + hh * 64 + lane] = __float2bfloat16(o);
    }
}

// ---------------- final copy ----------------
__global__ void copy_out(const float* __restrict__ h, float* __restrict__ out, int n) {
    int idx = blockIdx.x * 256 + threadIdx.x;
    if (idx < n) out[idx] = h[idx];
}

extern "C" void kernel_launch(void* const* d_in, const int* in_sizes, int n_in,
                              void* d_out, int out_size, void* d_ws, size_t ws_size,
                              hipStream_t stream) {
    const float* x      = (const float*)d_in[0];
    const float* conv_w = (const float*)d_in[1];
    const float* conv_b = (const float*)d_in[2];
    const float* cls_e  = (const float*)d_in[3];
    const float* pos_e  = (const float*)d_in[4];
    const float* ln1_s  = (const float*)d_in[5];
    const float* ln1_b  = (const float*)d_in[6];
    const float* qkv_w  = (const float*)d_in[7];
    const float* qkv_b  = (const float*)d_in[8];
    const float* proj_w = (const float*)d_in[9];
    const float* proj_b = (const float*)d_in[10];
    const float* ln2_s  = (const float*)d_in[11];
    const float* ln2_b  = (const float*)d_in[12];
    const float* fc1_w  = (const float*)d_in[13];
    const float* fc1_b  = (const float*)d_in[14];
    const float* fc2_w  = (const float*)d_in[15];
    const float* fc2_b  = (const float*)d_in[16];

    // Footprint per chunk: Mr * (h 3072 + y 3072 + att 1536 + max(qkv,mlp) 6144) bytes
    int imgs = BATCH;
    while (imgs > 1 && (size_t)imgs * NTOK * 13824ull > ws_size) imgs >>= 1;
    size_t Mr = (size_t)imgs * NTOK;

    float* h   = (float*)d_ws;
    float* y   = h + Mr * 768;
    bf16*  att = (bf16*)(y + Mr * 768);
    bf16*  big = att + Mr * 768;

    int Mi = (int)Mr;
    int gy = (Mi + 127) / 128;

    for (int b0 = 0; b0 < BATCH; b0 += imgs) {
        // patch embedding = im2col (into y scratch) + MFMA GEMM with pos/row-remap epilogue
        int Me = imgs * 196;
        im2col_k<<<dim3((Me * 96 + 255) / 256), 256, 0, stream>>>(x, y, b0, Me);
        gemm_mfma<float, float, 3><<<dim3(6, (Me + 127) / 128), 256, 0, stream>>>(
            y, 768, conv_w, 768, conv_b, pos_e, h, 768, Me, 768, /*wTrans|embedOut*/ 12);
        embed_cls<<<dim3(imgs), dim3(768), 0, stream>>>(cls_e, pos_e, h);

        for (int l = 0; l < LAYERS; ++l) {
            const float* qw  = qkv_w  + (long)l * HEADS * 768 * 192;
            const float* qb  = qkv_b  + (long)l * HEADS * 192;
            const float* pw  = proj_w + (long)l * 768 * 768;
            const float* pb  = proj_b + (long)l * 768;
            const float* f1w = fc1_w  + (long)l * 768 * 3072;
            const float* f1b = fc1_b  + (long)l * 3072;
            const float* f2w = fc2_w  + (long)l * 3072 * 768;
            const float* f2b = fc2_b  + (long)l * 768;

            layernorm_k<<<Mi, 256, 0, stream>>>(h, y, ln1_s + l * 768, ln1_b + l * 768);
            // qkv: [Mi,768] x per-head [768,192] flattened to N=2304 -> bf16
            gemm_mfma<float, bf16t, 3><<<dim3(18, gy), 256, 0, stream>>>(
                y, 768, qw, 192, qb, nullptr, (bf16t*)big, 2304, Mi, 768, /*perHead*/ 2);
            attn_k<<<dim3(25, HEADS, imgs), 256, 0, stream>>>(big, att);
            // proj + residual (in-place on h); A already bf16 -> 2-term
            gemm_mfma<bf16t, float, 2><<<dim3(6, gy), 256, 0, stream>>>(
                (const bf16t*)att, 768, pw, 768, pb, h, h, 768, Mi, 768, 0);
            layernorm_k<<<Mi, 256, 0, stream>>>(h, y, ln2_s + l * 768, ln2_b + l * 768);
            // fc1 + gelu -> bf16 hidden
            gemm_mfma<float, bf16t, 3><<<dim3(24, gy), 256, 0, stream>>>(
                y, 768, f1w, 3072, f1b, nullptr, (bf16t*)big, 3072, Mi, 768, /*gelu*/ 1);
            // fc2 + residual (in-place on h); A already bf16 -> 2-term
            gemm_mfma<bf16t, float, 2><<<dim3(6, gy), 256, 0, stream>>>(
                (const bf16t*)big, 3072, f2w, 768, f2b, h, h, 768, Mi, 3072, 0);
        }

        copy_out<<<(Mi * 768 + 255) / 256, 256, 0, stream>>>(
            h, (float*)d_out + (size_t)b0 * NTOK * 768, Mi * 768);
    }
}

// Round 3
// 11809.331 us; speedup vs baseline: 4.2488x; 2.1166x over previous
//
#include <hip/hip_runtime.h>
#include <hip/hip_bf16.h>
#include <math.h>

typedef __hip_bfloat16 bf16;
typedef __bf16 bf16t;
typedef __attribute__((ext_vector_type(8))) __bf16 bf16x8;
typedef __attribute__((ext_vector_type(4))) __bf16 bf16x4;
typedef __attribute__((ext_vector_type(16))) float f32x16;

#define E_DIM 768
#define HEADS 12
#define DHEAD 64
#define LAYERS 12
#define NTOK 197
#define BATCH 64
#define EPSV 1e-5f

// ---------------- im2col for patch embedding ----------------
__global__ __launch_bounds__(256) void im2col_k(const float* __restrict__ x,
                                                float* __restrict__ P,
                                                int b0, int M) {
    int task = blockIdx.x * 256 + threadIdx.x;
    if (task >= M * 96) return;
    int m = task / 96;
    int kg = task - m * 96;
    int k0 = kg * 8;
    int c = k0 >> 8, py = (k0 >> 4) & 15, px = k0 & 15;
    int bl = m / 196, pidx = m - bl * 196;
    int ph = pidx / 14, pw = pidx - ph * 14;
    const float* src = x + ((size_t)((b0 + bl) * 3 + c) * 224 + (ph * 16 + py)) * 224
                         + pw * 16 + px;
    const float4* s4 = reinterpret_cast<const float4*>(src);
    float4* d4 = reinterpret_cast<float4*>(P + (size_t)m * 768 + k0);
    d4[0] = s4[0];
    d4[1] = s4[1];
}

__global__ void embed_cls(const float* __restrict__ cls, const float* __restrict__ pos,
                          float* __restrict__ h) {
    int b = blockIdx.x, e = threadIdx.x;
    h[(size_t)b * NTOK * 768 + e] = cls[e] + pos[e];
}

// ---------------- layernorm over E=768: single pass, wave shfl reduce ----------------
__global__ __launch_bounds__(256) void layernorm_k(
    const float* __restrict__ h, float* __restrict__ y,
    const float* __restrict__ s, const float* __restrict__ bsh) {
    int tok = blockIdx.x, t = threadIdx.x;
    const float* row = h + (size_t)tok * 768;
    float v0 = row[t], v1 = row[t + 256], v2 = row[t + 512];
    float s1 = v0 + v1 + v2;
    float s2 = v0 * v0 + v1 * v1 + v2 * v2;
#pragma unroll
    for (int off = 32; off; off >>= 1) {
        s1 += __shfl_xor(s1, off);
        s2 += __shfl_xor(s2, off);
    }
    __shared__ float r1[4], r2[4];
    int wv = t >> 6, ln = t & 63;
    if (ln == 0) { r1[wv] = s1; r2[wv] = s2; }
    __syncthreads();
    s1 = r1[0] + r1[1] + r1[2] + r1[3];
    s2 = r2[0] + r2[1] + r2[2] + r2[3];
    float mean = s1 * (1.f / 768.f);
    float var = s2 * (1.f / 768.f) - mean * mean;
    float rs = rsqrtf(var + EPSV);
    float* yr = y + (size_t)tok * 768;
    yr[t]       = (v0 - mean) * rs * s[t]       + bsh[t];
    yr[t + 256] = (v1 - mean) * rs * s[t + 256] + bsh[t + 256];
    yr[t + 512] = (v2 - mean) * rs * s[t + 512] + bsh[t + 512];
}

// ---------------- MFMA helpers ----------------
__device__ __forceinline__ f32x16 mfma_bf16(bf16x8 a, bf16x8 b, f32x16 c) {
    return __builtin_amdgcn_mfma_f32_32x32x16_bf16(a, b, c, 0, 0, 0);
}
__device__ __forceinline__ f32x16 zero16() {
    f32x16 z;
#pragma unroll
    for (int i = 0; i < 16; ++i) z[i] = 0.f;
    return z;
}
__device__ __forceinline__ bf16x8 zbf8() {
    bf16x8 v;
#pragma unroll
    for (int i = 0; i < 8; ++i) v[i] = (__bf16)0.f;
    return v;
}
__device__ __forceinline__ unsigned pkbf(float a, float b) {
    unsigned short ua = __builtin_bit_cast(unsigned short, (__bf16)a);
    unsigned short ub = __builtin_bit_cast(unsigned short, (__bf16)b);
    return (unsigned)ua | ((unsigned)ub << 16);
}
__device__ __forceinline__ void split8(float4 u0, float4 u1, bf16x8& hi, bf16x8& lo) {
    float f[8] = {u0.x, u0.y, u0.z, u0.w, u1.x, u1.y, u1.z, u1.w};
#pragma unroll
    for (int j = 0; j < 8; ++j) {
        __bf16 h = (__bf16)f[j];
        hi[j] = h;
        lo[j] = (__bf16)(f[j] - (float)h);
    }
}

// ---------------- MFMA GEMM, split-bf16 accumulation ----------------
// flags: 1=gelu, 2=perHead (qkv W layout [H][K][192]), 4=wTrans (W [N][K]),
//        8=embedOut (row remap + pos), 16=qkvOut (deinterleave Q/K/V^T)
#define PLANE 2064

template <typename AT, typename CT, int TERMS>
__global__ __launch_bounds__(256, 2) void gemm_mfma(
    const AT* __restrict__ A, int lda,
    const float* __restrict__ W, int ldw,
    const float* __restrict__ bias,
    const float* __restrict__ resid,
    CT* __restrict__ C, int ldc,
    int M, int K, int flags) {
    constexpr bool SPLIT_A = (TERMS >= 3);
    const int gelu = flags & 1, perHead = flags & 2, wTrans = flags & 4;
    const int embedOut = flags & 8, qkvOut = flags & 16;
    const int n0 = blockIdx.x * 128, m0 = blockIdx.y * 128;
    const int t = threadIdx.x;

    size_t QKT = 0;
    if (qkvOut) QKT = (size_t)(M / 197) * 12 * 197 * 64;

    __shared__ __align__(16) char smem[SPLIT_A ? 4 * 8256 : 3 * 8256];
    char* sAh = smem;
    char* sWh = smem + 8256;
    char* sWl = smem + 16512;
    char* sAl = SPLIT_A ? smem + 24768 : smem;

    const AT* aptr[2]; int aoff[2]; bool aok[2];
    const float* wptr[2]; int woff[2];
    const size_t wstep = perHead ? 192 : (size_t)ldw;
#pragma unroll
    for (int p = 0; p < 2; ++p) {
        int q = t + p * 256;
        int rn = q & 127, kg = q >> 7;
        int gm = m0 + rn;
        aok[p] = gm < M;
        aptr[p] = A + (size_t)(aok[p] ? gm : 0) * lda + kg * 8;
        aoff[p] = kg * PLANE + rn * 16;
        woff[p] = kg * PLANE + rn * 16;
        if (wTrans) {
            wptr[p] = W + (size_t)(n0 + rn) * ldw + kg * 8;
        } else if (perHead) {
            int gn = n0 + rn;
            int hh = gn / 192;
            wptr[p] = W + (size_t)hh * K * 192 + (gn - hh * 192) + (size_t)(kg * 8) * 192;
        } else {
            wptr[p] = W + (n0 + rn) + (size_t)(kg * 8) * ldw;
        }
    }

    const int lane = t & 63, wv = t >> 6;
    const int wm = wv >> 1, wn = wv & 1;
    const int lr = lane & 31, lk = lane >> 5;
    const int arow0 = (wm * 64 + lr) * 16;
    const int brow0 = (wn * 64 + lr) * 16;
    f32x16 acc00 = zero16(), acc01 = zero16(), acc10 = zero16(), acc11 = zero16();

    const int nIt = K >> 5;
    for (int it = 0; it < nIt; ++it) {
        const int k0 = it << 5;
        __syncthreads();
#pragma unroll
        for (int p = 0; p < 2; ++p) {
            if constexpr (sizeof(AT) == 4) {
                float4 u0 = make_float4(0.f, 0.f, 0.f, 0.f), u1 = u0;
                if (aok[p]) {
                    const float4* s4 = reinterpret_cast<const float4*>(aptr[p] + k0);
                    u0 = s4[0]; u1 = s4[1];
                }
                bf16x8 hi, lo;
                split8(u0, u1, hi, lo);
                *reinterpret_cast<bf16x8*>(sAh + aoff[p]) = hi;
                if constexpr (SPLIT_A) *reinterpret_cast<bf16x8*>(sAl + aoff[p]) = lo;
            } else {
                bf16x8 hi = zbf8();
                if (aok[p]) hi = *reinterpret_cast<const bf16x8*>(aptr[p] + k0);
                *reinterpret_cast<bf16x8*>(sAh + aoff[p]) = hi;
            }
        }
#pragma unroll
        for (int p = 0; p < 2; ++p) {
            bf16x8 hi, lo;
            if (wTrans) {
                const float4* s4 = reinterpret_cast<const float4*>(wptr[p] + k0);
                split8(s4[0], s4[1], hi, lo);
            } else {
                const float* s = wptr[p] + (size_t)k0 * wstep;
                float4 u0, u1;
                u0.x = s[0];         u0.y = s[wstep];     u0.z = s[2 * wstep]; u0.w = s[3 * wstep];
                u1.x = s[4 * wstep]; u1.y = s[5 * wstep]; u1.z = s[6 * wstep]; u1.w = s[7 * wstep];
                split8(u0, u1, hi, lo);
            }
            *reinterpret_cast<bf16x8*>(sWh + woff[p]) = hi;
            *reinterpret_cast<bf16x8*>(sWl + woff[p]) = lo;
        }
        __syncthreads();
#pragma unroll
        for (int ks = 0; ks < 2; ++ks) {
            const int kg = ks * 2 + lk;
            const char* pa  = sAh + kg * PLANE;
            const char* pb  = sWh + kg * PLANE;
            const char* pbl = sWl + kg * PLANE;
            bf16x8 ah0 = *reinterpret_cast<const bf16x8*>(pa + arow0);
            bf16x8 ah1 = *reinterpret_cast<const bf16x8*>(pa + arow0 + 512);
            bf16x8 bh0 = *reinterpret_cast<const bf16x8*>(pb + brow0);
            bf16x8 bh1 = *reinterpret_cast<const bf16x8*>(pb + brow0 + 512);
            bf16x8 bl0 = *reinterpret_cast<const bf16x8*>(pbl + brow0);
            bf16x8 bl1 = *reinterpret_cast<const bf16x8*>(pbl + brow0 + 512);
            acc00 = mfma_bf16(ah0, bh0, acc00);
            acc01 = mfma_bf16(ah0, bh1, acc01);
            acc10 = mfma_bf16(ah1, bh0, acc10);
            acc11 = mfma_bf16(ah1, bh1, acc11);
            acc00 = mfma_bf16(ah0, bl0, acc00);
            acc01 = mfma_bf16(ah0, bl1, acc01);
            acc10 = mfma_bf16(ah1, bl0, acc10);
            acc11 = mfma_bf16(ah1, bl1, acc11);
            if constexpr (SPLIT_A) {
                const char* pal = sAl + kg * PLANE;
                bf16x8 al0 = *reinterpret_cast<const bf16x8*>(pal + arow0);
                bf16x8 al1 = *reinterpret_cast<const bf16x8*>(pal + arow0 + 512);
                acc00 = mfma_bf16(al0, bh0, acc00);
                acc01 = mfma_bf16(al0, bh1, acc01);
                acc10 = mfma_bf16(al1, bh0, acc10);
                acc11 = mfma_bf16(al1, bh1, acc11);
            }
        }
    }

    const int gcol0 = n0 + wn * 64 + lr;
#define EPILOG(ACC, MF, NF)                                                         \
    {                                                                               \
        int gcol = gcol0 + (NF) * 32;                                               \
        float bv = bias[gcol];                                                      \
        int hh2 = gcol / 192;                                                       \
        int k2 = gcol - 192 * hh2;                                                  \
        int d2 = k2 / 3;                                                            \
        int r2 = k2 - 3 * d2;                                                       \
        _Pragma("unroll")                                                           \
        for (int r = 0; r < 16; ++r) {                                              \
            int grow = m0 + wm * 64 + (MF) * 32 + (r & 3) + 8 * (r >> 2) + 4 * lk;  \
            if (grow < M) {                                                         \
                float val = ACC[r] + bv;                                            \
                if (gelu) val = 0.5f * val * (1.f + erff(val * 0.70710678f));       \
                if (qkvOut) {                                                       \
                    int b2 = grow / 197, n2 = grow - 197 * b2;                      \
                    int bh2 = b2 * 12 + hh2;                                        \
                    if (r2 == 2)                                                    \
                        C[2 * QKT + ((size_t)bh2 * 64 + d2) * 208 + n2] = (CT)val;  \
                    else                                                            \
                        C[(r2 ? QKT : 0) + ((size_t)bh2 * 197 + n2) * 64 + d2] = (CT)val; \
                } else if (embedOut) {                                              \
                    int bl2 = grow / 196;                                           \
                    int pidx = grow - bl2 * 196;                                    \
                    val += resid[(size_t)(pidx + 1) * 768 + gcol];                  \
                    C[((size_t)bl2 * 197 + pidx + 1) * ldc + gcol] = (CT)val;       \
                } else {                                                            \
                    if (resid) val += resid[(size_t)grow * ldc + gcol];             \
                    C[(size_t)grow * ldc + gcol] = (CT)val;                         \
                }                                                                   \
            }                                                                       \
        }                                                                           \
    }
    EPILOG(acc00, 0, 0)
    EPILOG(acc01, 0, 1)
    EPILOG(acc10, 1, 0)
    EPILOG(acc11, 1, 1)
#undef EPILOG
}

// ---------------- MFMA fused attention ----------------
// One block per (b,h). K [224][64] and V^T [64][256] staged in XOR-swizzled LDS.
// Swapped QK^T (S^T = K·Q^T) -> in-register softmax (q lane-local) ->
// bf16 P pack + shfl_xor(32) redistribution -> O^T = V^T·P^T -> LDS transpose -> out.
#define AKOFF 0
#define AVOFF 28672
#define AOOFF 61440
#define AOSTR 152
#define AOWAVE 4864

__global__ __launch_bounds__(256) void attn_mfma(
    const bf16t* __restrict__ Qb, const bf16t* __restrict__ Kb,
    const bf16t* __restrict__ Vg, bf16t* __restrict__ att) {
    __shared__ __align__(16) char lds[80896];
    const int bh = blockIdx.x;
    const int b = bh / 12, h = bh - b * 12;
    const int t = threadIdx.x;
    const int lane = t & 63, wv = t >> 6;
    const int lr = lane & 31, lk = lane >> 5;
    const int xorv = (lr & 7) << 4;

    // stage K: rows 0..223 (>=197 zero), row = 128 B, swizzled
    {
        const bf16t* kb = Kb + (size_t)bh * 197 * 64;
#pragma unroll
        for (int c = 0; c < 7; ++c) {
            int idx = c * 256 + t;
            int row = idx >> 3, d8 = idx & 7;
            bf16x8 v = zbf8();
            if (row < 197) v = *(const bf16x8*)(kb + (size_t)row * 64 + d8 * 8);
            *(bf16x8*)(lds + AKOFF + row * 128 + ((d8 * 16) ^ ((row & 7) << 4))) = v;
        }
    }
    // stage V^T: 64 rows x 256 elems (kk >= 197 zero), row = 512 B, swizzled
    {
        const bf16t* vb = Vg + (size_t)bh * 64 * 208;
#pragma unroll
        for (int c = 0; c < 8; ++c) {
            int idx = c * 256 + t;
            int dv = idx >> 5, cc = idx & 31;
            bf16x8 v = zbf8();
            if (cc < 25) {
                v = *(const bf16x8*)(vb + (size_t)dv * 208 + cc * 8);
                if (cc == 24) { v[5] = (__bf16)0.f; v[6] = (__bf16)0.f; v[7] = (__bf16)0.f; }
            }
            *(bf16x8*)(lds + AVOFF + dv * 512 + ((cc * 16) ^ ((dv & 7) << 4))) = v;
        }
    }
    __syncthreads();

    const bf16t* qb = Qb + (size_t)bh * 197 * 64;
    char* olds = lds + AOOFF + wv * AOWAVE;

    for (int tt = wv; tt < 7; tt += 4) {
        const int i0 = tt * 32;
        int qrow = i0 + lr; if (qrow > 196) qrow = 196;
        bf16x8 qf[4];
#pragma unroll
        for (int s = 0; s < 4; ++s)
            qf[s] = *(const bf16x8*)(qb + (size_t)qrow * 64 + s * 16 + lk * 8);

        f32x16 acc[7];
#pragma unroll
        for (int kt = 0; kt < 7; ++kt) acc[kt] = zero16();
#pragma unroll
        for (int kt = 0; kt < 7; ++kt) {
#pragma unroll
            for (int s = 0; s < 4; ++s) {
                bf16x8 aK = *(const bf16x8*)(lds + AKOFF + (kt * 32 + lr) * 128
                                             + (((s * 16 + lk * 8) * 2) ^ xorv));
                acc[kt] = mfma_bf16(aK, qf[s], acc[kt]);
            }
        }
        // softmax (per lane: column q = lr; halves combined via shfl_xor 32)
        float mx = -1e30f;
#pragma unroll
        for (int kt = 0; kt < 7; ++kt)
#pragma unroll
            for (int r = 0; r < 16; ++r) {
                int kk = kt * 32 + (r & 3) + 8 * (r >> 2) + 4 * lk;
                if (kk >= 197) acc[kt][r] = -1e30f;
                mx = fmaxf(mx, acc[kt][r]);
            }
        mx = fmaxf(mx, __shfl_xor(mx, 32));
        float sum = 0.f;
#pragma unroll
        for (int kt = 0; kt < 7; ++kt)
#pragma unroll
            for (int r = 0; r < 16; ++r) {
                float e = __expf((acc[kt][r] - mx) * 0.125f);
                acc[kt][r] = e;
                sum += e;
            }
        sum += __shfl_xor(sum, 32);
        float inv = 1.f / sum;

        // PV: O^T = V^T · P^T
        f32x16 accO0 = zero16(), accO1 = zero16();
#pragma unroll
        for (int s = 0; s < 14; ++s) {
            const int kt = s >> 1, bb = (s & 1) * 8;
            unsigned A0 = pkbf(acc[kt][bb + 0], acc[kt][bb + 1]);
            unsigned A1 = pkbf(acc[kt][bb + 2], acc[kt][bb + 3]);
            unsigned C0 = pkbf(acc[kt][bb + 4], acc[kt][bb + 5]);
            unsigned C1 = pkbf(acc[kt][bb + 6], acc[kt][bb + 7]);
            unsigned x = lk ? A0 : C0, y = lk ? A1 : C1;
            unsigned rx = __shfl_xor(x, 32), ry = __shfl_xor(y, 32);
            union { unsigned u[4]; bf16x8 v; } fr;
            fr.u[0] = lk ? rx : A0; fr.u[1] = lk ? ry : A1;
            fr.u[2] = lk ? C0 : rx; fr.u[3] = lk ? C1 : ry;
            const int voff = ((s * 16 + lk * 8) * 2) ^ xorv;
            bf16x8 aV0 = *(const bf16x8*)(lds + AVOFF + lr * 512 + voff);
            bf16x8 aV1 = *(const bf16x8*)(lds + AVOFF + (lr + 32) * 512 + voff);
            accO0 = mfma_bf16(aV0, fr.v, accO0);
            accO1 = mfma_bf16(aV1, fr.v, accO1);
        }
        // O^T -> per-wave LDS (row q = lr), scaled by 1/l
#pragma unroll
        for (int r = 0; r < 16; r += 2) {
            int dvb = (r & 3) + 8 * (r >> 2) + 4 * lk;
            unsigned u0 = pkbf(accO0[r] * inv, accO0[r + 1] * inv);
            unsigned u1 = pkbf(accO1[r] * inv, accO1[r + 1] * inv);
            *(unsigned*)(olds + lr * AOSTR + dvb * 2) = u0;
            *(unsigned*)(olds + lr * AOSTR + (dvb + 32) * 2) = u1;
        }
        asm volatile("s_waitcnt lgkmcnt(0)" ::: "memory");
        // coalesced writeout
#pragma unroll
        for (int c = 0; c < 8; ++c) {
            int cid = c * 64 + lane;
            int q = cid >> 4, dc = cid & 15;
            bf16x4 v = *(const bf16x4*)(olds + q * AOSTR + dc * 8);
            int gq = i0 + q;
            if (gq < 197)
                *(bf16x4*)(att + ((size_t)b * 197 + gq) * 768 + h * 64 + dc * 4) = v;
        }
    }
}

extern "C" void kernel_launch(void* const* d_in, const int* in_sizes, int n_in,
                              void* d_out, int out_size, void* d_ws, size_t ws_size,
                              hipStream_t stream) {
    const float* x      = (const float*)d_in[0];
    const float* conv_w = (const float*)d_in[1];
    const float* conv_b = (const float*)d_in[2];
    const float* cls_e  = (const float*)d_in[3];
    const float* pos_e  = (const float*)d_in[4];
    const float* ln1_s  = (const float*)d_in[5];
    const float* ln1_b  = (const float*)d_in[6];
    const float* qkv_w  = (const float*)d_in[7];
    const float* qkv_b  = (const float*)d_in[8];
    const float* proj_w = (const float*)d_in[9];
    const float* proj_b = (const float*)d_in[10];
    const float* ln2_s  = (const float*)d_in[11];
    const float* ln2_b  = (const float*)d_in[12];
    const float* fc1_w  = (const float*)d_in[13];
    const float* fc1_b  = (const float*)d_in[14];
    const float* fc2_w  = (const float*)d_in[15];
    const float* fc2_b  = (const float*)d_in[16];

    int imgs = BATCH;
    while (imgs > 1 && (size_t)imgs * NTOK * 13824ull > ws_size) imgs >>= 1;
    size_t Mr = (size_t)imgs * NTOK;

    float* h   = (float*)d_ws;
    float* y   = h + Mr * 768;
    bf16*  att = (bf16*)(y + Mr * 768);
    bf16*  big = att + Mr * 768;

    int Mi = (int)Mr;
    int gy = (Mi + 127) / 128;
    size_t QKTOT = (size_t)imgs * 12 * 197 * 64;   // Q / K buffer elems; V^T follows

    for (int b0 = 0; b0 < BATCH; b0 += imgs) {
        int Me = imgs * 196;
        im2col_k<<<dim3((Me * 96 + 255) / 256), 256, 0, stream>>>(x, y, b0, Me);
        gemm_mfma<float, float, 3><<<dim3(6, (Me + 127) / 128), 256, 0, stream>>>(
            y, 768, conv_w, 768, conv_b, pos_e, h, 768, Me, 768, /*wTrans|embedOut*/ 12);
        embed_cls<<<dim3(imgs), dim3(768), 0, stream>>>(cls_e, pos_e, h);

        for (int l = 0; l < LAYERS; ++l) {
            const float* qw  = qkv_w  + (long)l * HEADS * 768 * 192;
            const float* qb  = qkv_b  + (long)l * HEADS * 192;
            const float* pw  = proj_w + (long)l * 768 * 768;
            const float* pb  = proj_b + (long)l * 768;
            const float* f1w = fc1_w  + (long)l * 768 * 3072;
            const float* f1b = fc1_b  + (long)l * 3072;
            const float* f2w = fc2_w  + (long)l * 3072 * 768;
            const float* f2b = fc2_b  + (long)l * 768;

            layernorm_k<<<Mi, 256, 0, stream>>>(h, y, ln1_s + l * 768, ln1_b + l * 768);
            // qkv -> deinterleaved Q [bh][197][64], K [bh][197][64], V^T [bh][64][208]
            gemm_mfma<float, bf16t, 3><<<dim3(18, gy), 256, 0, stream>>>(
                y, 768, qw, 192, qb, nullptr, (bf16t*)big, 2304, Mi, 768, /*perHead|qkvOut*/ 18);
            attn_mfma<<<dim3(imgs * 12), 256, 0, stream>>>(
                (const bf16t*)big, (const bf16t*)big + QKTOT,
                (const bf16t*)big + 2 * QKTOT, (bf16t*)att);
            gemm_mfma<bf16t, float, 2><<<dim3(6, gy), 256, 0, stream>>>(
                (const bf16t*)att, 768, pw, 768, pb, h, h, 768, Mi, 768, 0);
            layernorm_k<<<Mi, 256, 0, stream>>>(h, y, ln2_s + l * 768, ln2_b + l * 768);
            gemm_mfma<float, bf16t, 3><<<dim3(24, gy), 256, 0, stream>>>(
                y, 768, f1w, 3072, f1b, nullptr, (bf16t*)big, 3072, Mi, 768, /*gelu*/ 1);
            // last layer: fc2 writes straight to d_out (resid = h), else in-place on h
            float* outC = (l == LAYERS - 1)
                        ? (float*)d_out + (size_t)b0 * NTOK * 768 : h;
            const float* outR = h;
            gemm_mfma<bf16t, float, 2><<<dim3(6, gy), 256, 0, stream>>>(
                (const bf16t*)big, 3072, f2w, 768, f2b, outR, outC, 768, Mi, 3072, 0);
        }
    }
}